// Round 17
// baseline (245.634 us; speedup 1.0000x reference)
//
#include <hip/hip_runtime.h>
#include <math.h>

constexpr int N = 50000;   // nodes
constexpr int E = 640000;  // edges
constexpr int D = 128;     // dim == hidden
constexpr int T = 100;     // targets per head
constexpr int NB = (N + 255) / 256;  // 196 dinv blocks
constexpr int MAXDEG = 64; // slot capacity; P(Poisson(12.8) >= 64) ~ 1e-24/node
// Per-layer f16 scale: h stored as 256*h. Folded exactly into W1 and biases.
constexpr float SC = 256.0f;
constexpr float SCINV = 1.0f / 256.0f;

typedef __attribute__((ext_vector_type(8))) _Float16 half8v;         // 8 f16 in 4 VGPRs
typedef __attribute__((ext_vector_type(8))) unsigned short ushort8v;
typedef __attribute__((ext_vector_type(4))) float f32x4;             // MFMA accumulator

// ---------------- single-pass edge build: histogram + rank-scatter ----------------
// One 64-bit atomicAdd per edge: high32 accumulates ew in 8.24 fixed (degree),
// low32 counts; the RETURN value's low word is this edge's rank within dst ->
// scatter (ew16|src) into slot[d*MAXDEG+rank]. No second edge pass, no scan.
// (R13 lesson: separate dispatches, never grid.sync on gfx950.)

__global__ void edge_pass_kernel(const float* __restrict__ ew, const int* __restrict__ src,
                                 const int* __restrict__ dst,
                                 unsigned long long* __restrict__ degcnt,
                                 unsigned int* __restrict__ slot) {
  int e = blockIdx.x * 256 + threadIdx.x;
  if (e < E) {
    float w = ew[e];
    int d = dst[e];
    unsigned int fxdeg = __float2uint_rn(w * 16777216.0f);       // 8.24 for degree
    unsigned int fx16 = __float2uint_rn(w * 65536.0f);           // 0.16 for agg coef
    if (fx16 > 65535u) fx16 = 65535u;
    unsigned long long old = atomicAdd(&degcnt[d],
                                       ((unsigned long long)fxdeg << 32) | 1ull);
    unsigned int rank = (unsigned int)(old & 0xffffffffull);
    if (rank < MAXDEG)
      slot[(size_t)d * MAXDEG + rank] = (fx16 << 16) | (unsigned int)src[e];
  }
}

// ---------------- prep: dinv (blocks < NB) + W f16 prep (blocks >= NB) ----------------

__global__ __launch_bounds__(256) void prep_kernel(
    const uint2* __restrict__ degcnt, float* __restrict__ dinv,
    const float* __restrict__ W0, const float* __restrict__ W1,
    const float* __restrict__ W2, unsigned short* __restrict__ wt,
    unsigned short* __restrict__ w3kn) {
  if (blockIdx.x < NB) {
    int i = blockIdx.x * 256 + threadIdx.x;
    if (i < N) {
      uint2 p = degcnt[i];                    // .x = count, .y = 8.24 degree sum
      float d = (float)p.y * (1.0f / 16777216.0f) + 1.0f;  // +1 self-loop
      dinv[i] = 1.0f / sqrtf(d);
    }
  } else {
    int idx = (blockIdx.x - NB) * 256 + threadIdx.x;  // 0..49151
    int layer = idx >> 14;
    int r = idx & 16383;
    int k = r & 127, n = r >> 7;
    const float* W = layer == 0 ? W0 : layer == 1 ? W1 : W2;
    float v = W[k * D + n] * (layer == 0 ? SC : 1.0f);
    _Float16 h = (_Float16)v;  // RNE
    unsigned short bits = *(unsigned short*)&h;
    wt[layer * 16384 + n * D + k] = bits;
    if (layer == 2) w3kn[k * D + n] = bits;
  }
}

// ---------------- shared MFMA pieces ----------------

__device__ inline void stage_B(const unsigned short* __restrict__ Wt,
                               unsigned short* __restrict__ Bl, int tid) {
  constexpr int SB = 136;
#pragma unroll
  for (int it = 0; it < 8; ++it) {
    int idx = tid + it * 256;          // ushort8 index, 0..2047
    int r = idx >> 4;
    int c8 = idx & 15;
    ushort8v v = *(const ushort8v*)&Wt[r * D + c8 * 8];
    *(ushort8v*)&Bl[r * SB + c8 * 8] = v;
  }
}

__device__ inline void mfma_core_and_store(
    const unsigned short* __restrict__ Bl, half8v (*a)[2], const float* __restrict__ dinv,
    int row0, int rbase, int q, int n16, unsigned short* __restrict__ out) {
  constexpr int SB = 136;
  f32x4 acc[2][8] = {};
#pragma unroll
  for (int kc = 0; kc < 4; ++kc) {
    const int ko = kc * 32 + q * 8;
#pragma unroll
    for (int ct = 0; ct < 8; ++ct) {
      int n = ct * 16 + n16;
      half8v b = *(const half8v*)&Bl[n * SB + ko];
#pragma unroll
      for (int rt = 0; rt < 2; ++rt) {
        acc[rt][ct] = __builtin_amdgcn_mfma_f32_16x16x32_f16(a[kc][rt], b, acc[rt][ct], 0, 0, 0);
      }
    }
  }
#pragma unroll
  for (int rt = 0; rt < 2; ++rt) {
#pragma unroll
    for (int r = 0; r < 4; ++r) {
      int gr = row0 + rbase + rt * 16 + q * 4 + r;
      if (gr < N) {
        float dv = dinv[gr];
#pragma unroll
        for (int ct = 0; ct < 8; ++ct) {
          int col = ct * 16 + n16;
          _Float16 h = (_Float16)(acc[rt][ct][r] * dv);
          out[(size_t)gr * D + col] = *(unsigned short*)&h;
        }
      }
    }
  }
}

// ---------------- layer-1 GEMM: fp32 x -> z1 = dinv*(x @ 256*W1), f16 out ----------------

__global__ __launch_bounds__(256) void gemm_mfma_f32_kernel(
    const float* __restrict__ A, const unsigned short* __restrict__ Wt,
    const float* __restrict__ dinv, unsigned short* __restrict__ out) {
  constexpr int SB = 136;
  __shared__ unsigned short Bl[128 * SB];
  const int tid = threadIdx.x;
  const int row0 = blockIdx.x * 128;
  stage_B(Wt, Bl, tid);
  __syncthreads();

  const int w = tid >> 6, lane = tid & 63;
  const int q = lane >> 4, n16 = lane & 15;
  const int rbase = w * 32;
  size_t arow[2];
#pragma unroll
  for (int rt = 0; rt < 2; ++rt) {
    int gr = row0 + rbase + rt * 16 + n16;
    if (gr >= N) gr = N - 1;
    arow[rt] = (size_t)gr * D;
  }
  half8v a[4][2];
#pragma unroll
  for (int kc = 0; kc < 4; ++kc) {
    const int ko = kc * 32 + q * 8;
#pragma unroll
    for (int rt = 0; rt < 2; ++rt) {
      float4 v0 = *(const float4*)&A[arow[rt] + ko];
      float4 v1 = *(const float4*)&A[arow[rt] + ko + 4];
      half8v h;
      h[0] = (_Float16)v0.x; h[1] = (_Float16)v0.y;
      h[2] = (_Float16)v0.z; h[3] = (_Float16)v0.w;
      h[4] = (_Float16)v1.x; h[5] = (_Float16)v1.y;
      h[6] = (_Float16)v1.z; h[7] = (_Float16)v1.w;
      a[kc][rt] = h;
    }
  }
  mfma_core_and_store(Bl, a, dinv, row0, rbase, q, n16, out);
}

// ---------------- fused agg1 + gemm2: z1 -> h1 (LDS tile) -> z2 ----------------
// Phase A: per 128-row tile, compute h1[g] = relu(dinv_g*(z1[g]+sum ew*z1[src]) + 256*b1)
// into LDS (f16, same RNE as the old P1 round-trip -> bit-identical numerics).
// Phase B: MFMA vs LDS-staged W2, z2 = dinv*(h1@W2). No P1 buffer, one dispatch fewer.
// LDS = 34.8 KB (W2) + 34.8 KB (h1 tile) -> 2 blocks/CU.

__global__ __launch_bounds__(256) void agg_gemm_kernel(
    const unsigned short* __restrict__ z1, const unsigned int* __restrict__ slot,
    const uint2* __restrict__ degcnt, const float* __restrict__ dinv,
    const float* __restrict__ bias, const unsigned short* __restrict__ Wt,
    unsigned short* __restrict__ out) {
  constexpr int SB = 136;
  __shared__ unsigned short Bl[128 * SB];   // W2 [n][k]
  __shared__ unsigned short Xl[128 * SB];   // h1 tile [r][k]
  const int tid = threadIdx.x;
  const int row0 = blockIdx.x * 128;
  stage_B(Wt, Bl, tid);

  // Phase A: aggregate 128 rows, 16 nodes per pass (16 lanes each)
  const int grp = tid >> 4, lane = tid & 15;
  float bl[8];
#pragma unroll
  for (int i = 0; i < 8; ++i) bl[i] = bias[lane * 8 + i] * SC;

#pragma unroll
  for (int pass = 0; pass < 8; ++pass) {
    int r = pass * 16 + grp;           // tile row 0..127
    int g = row0 + r; if (g >= N) g = N - 1;   // clamped dup rows; store guarded later
    int cnt = (int)degcnt[g].x; if (cnt > MAXDEG) cnt = MAXDEG;
    half8v xv = *(const half8v*)&z1[(size_t)g * D + lane * 8];
    float acc[8];
#pragma unroll
    for (int i = 0; i < 8; ++i) acc[i] = (float)xv[i];  // self term z1(g)
    const unsigned int* sl = slot + (size_t)g * MAXDEG;
    int k = 0;
    for (; k + 2 <= cnt; k += 2) {
      unsigned int p0 = sl[k], p1 = sl[k + 1];
      float c0 = (float)(p0 >> 16) * (1.0f / 65536.0f);
      float c1 = (float)(p1 >> 16) * (1.0f / 65536.0f);
      half8v v0 = *(const half8v*)&z1[(size_t)(p0 & 0xffffu) * D + lane * 8];
      half8v v1 = *(const half8v*)&z1[(size_t)(p1 & 0xffffu) * D + lane * 8];
#pragma unroll
      for (int i = 0; i < 8; ++i) {
        acc[i] = fmaf(c0, (float)v0[i], acc[i]);
        acc[i] = fmaf(c1, (float)v1[i], acc[i]);
      }
    }
    if (k < cnt) {
      unsigned int p = sl[k];
      float c = (float)(p >> 16) * (1.0f / 65536.0f);
      half8v v = *(const half8v*)&z1[(size_t)(p & 0xffffu) * D + lane * 8];
#pragma unroll
      for (int i = 0; i < 8; ++i) acc[i] = fmaf(c, (float)v[i], acc[i]);
    }
    float dv = dinv[g];
    ushort8v hv;
#pragma unroll
    for (int i = 0; i < 8; ++i) {
      _Float16 h = (_Float16)fmaxf(fmaf(dv, acc[i], bl[i]), 0.f);
      hv[i] = *(unsigned short*)&h;
    }
    *(ushort8v*)&Xl[r * SB + lane * 8] = hv;
  }
  __syncthreads();

  // Phase B: MFMA, A fragments from the LDS h1 tile
  const int w = tid >> 6, lane64 = tid & 63;
  const int q = lane64 >> 4, n16 = lane64 & 15;
  const int rbase = w * 32;
  half8v a[4][2];
#pragma unroll
  for (int kc = 0; kc < 4; ++kc) {
    const int ko = kc * 32 + q * 8;
#pragma unroll
    for (int rt = 0; rt < 2; ++rt)
      a[kc][rt] = *(const half8v*)&Xl[(rbase + rt * 16 + n16) * SB + ko];
  }
  mfma_core_and_store(Bl, a, dinv, row0, rbase, q, n16, out);
}

// ---------------- fused layers 2+3 + dense + heads, per target ----------------
// h2z(u) = dinv_u * relu(dinv_u*[z2(u)+sum ew*z2(s)] + 256*b2)
// svec   = dinv_t * [h2z(t) + sum ew*h2z(src)]
// h3 = relu(svec@W3 + 256*b3)/256; h4 = relu(h3@Wh+bh); out = h4.whead + bhead.

__global__ __launch_bounds__(256) void l23_heads_kernel(
    const unsigned short* __restrict__ z2, const unsigned int* __restrict__ slot,
    const uint2* __restrict__ degcnt, const float* __restrict__ dinv,
    const float* __restrict__ b2, const float* __restrict__ b3,
    const unsigned short* __restrict__ w3kn,
    const float* __restrict__ Wh, const float* __restrict__ bh,
    const int* __restrict__ ace_idx, const int* __restrict__ h2_idx,
    const float* __restrict__ Wace, const float* __restrict__ bace,
    const float* __restrict__ Wh2, const float* __restrict__ bh2,
    float* __restrict__ out) {
  __shared__ float sacc[16][128];        // per-group partial svec (pre dinv_t)
  __shared__ unsigned short w3l[16384];  // W3 [k][n] f16, 32 KB
  __shared__ float svec[128];
  __shared__ float h3v[128];
  __shared__ float psum[2];
  int t = blockIdx.x;       // 0..2T-1
  int tid = threadIdx.x;    // 0..255
  int node; const float* whead; float bhead;
  if (t < T) { node = ace_idx[t];     whead = Wace; bhead = bace[0]; }
  else       { node = h2_idx[t - T];  whead = Wh2;  bhead = bh2[0]; }

#pragma unroll
  for (int it = 0; it < 8; ++it) {
    int idx = tid + it * 256;
    *(ushort8v*)&w3l[idx * 8] = *(const ushort8v*)&w3kn[idx * 8];
  }

  int grp = tid >> 4, lane = tid & 15;
  float b2l[8];
#pragma unroll
  for (int i = 0; i < 8; ++i) b2l[i] = b2[lane * 8 + i] * SC;

  int tcnt = (int)degcnt[node].x; if (tcnt > MAXDEG) tcnt = MAXDEG;
  const unsigned int* tsl = slot + (size_t)node * MAXDEG;
  int nitems = 1 + tcnt;
  float a[8] = {};
  for (int it = grp; it < nitems; it += 16) {
    int u; float wgt;
    if (it == 0) { u = node; wgt = 1.0f; }
    else {
      unsigned int p = tsl[it - 1];
      wgt = (float)(p >> 16) * (1.0f / 65536.0f);
      u = (int)(p & 0xffffu);
    }
    // h2z(u) on the fly
    float dvu = dinv[u];
    half8v xv = *(const half8v*)&z2[(size_t)u * D + lane * 8];
    float r[8];
#pragma unroll
    for (int i = 0; i < 8; ++i) r[i] = (float)xv[i];
    int cu = (int)degcnt[u].x; if (cu > MAXDEG) cu = MAXDEG;
    const unsigned int* usl = slot + (size_t)u * MAXDEG;
    for (int e = 0; e < cu; ++e) {
      unsigned int p2 = usl[e];
      float c2 = (float)(p2 >> 16) * (1.0f / 65536.0f);
      half8v v = *(const half8v*)&z2[(size_t)(p2 & 0xffffu) * D + lane * 8];
#pragma unroll
      for (int i = 0; i < 8; ++i) r[i] = fmaf(c2, (float)v[i], r[i]);
    }
#pragma unroll
    for (int i = 0; i < 8; ++i) {
      float h2 = fmaxf(fmaf(dvu, r[i], b2l[i]), 0.f);
      a[i] = fmaf(wgt, dvu * h2, a[i]);    // accumulate ew * h2z
    }
  }
#pragma unroll
  for (int i = 0; i < 8; ++i) sacc[grp][lane * 8 + i] = a[i];
  __syncthreads();

  // reduce 16 groups -> svec (apply dinv_t here)
  if (tid < 128) {
    float s = 0.f;
#pragma unroll
    for (int gp = 0; gp < 16; ++gp) s += sacc[gp][tid];
    svec[tid] = s * dinv[node];
  }
  __syncthreads();

  if (tid < 128) {
    float y = b3[tid] * SC;
#pragma unroll 16
    for (int k = 0; k < 128; ++k) {
      _Float16 wv = *(const _Float16*)&w3l[k * D + tid];
      y = fmaf(svec[k], (float)wv, y);
    }
    h3v[tid] = fmaxf(y, 0.f) * SCINV;
  }
  __syncthreads();

  float v = 0.f;
  if (tid < 128) {
    float acc = bh[tid];
#pragma unroll 16
    for (int k = 0; k < 128; ++k)
      acc = fmaf(h3v[k], Wh[k * D + tid], acc);
    v = fmaxf(acc, 0.f) * whead[tid];
  }
#pragma unroll
  for (int off = 32; off; off >>= 1) v += __shfl_down(v, off, 64);
  if (tid < 128 && (tid & 63) == 0) psum[tid >> 6] = v;
  __syncthreads();
  if (tid == 0) out[t] = psum[0] + psum[1] + bhead;
}

// ---------------- launch ----------------

extern "C" void kernel_launch(void* const* d_in, const int* in_sizes, int n_in,
                              void* d_out, int out_size, void* d_ws, size_t ws_size,
                              hipStream_t stream) {
  const float* x    = (const float*)d_in[0];
  const int*   ei   = (const int*)d_in[1];
  const float* ew   = (const float*)d_in[2];
  const int*   ace  = (const int*)d_in[3];
  const int*   h2   = (const int*)d_in[4];
  const float* W1 = (const float*)d_in[5];  const float* b1 = (const float*)d_in[6];
  const float* W2 = (const float*)d_in[7];  const float* b2 = (const float*)d_in[8];
  const float* W3 = (const float*)d_in[9];  const float* b3 = (const float*)d_in[10];
  const float* Wh = (const float*)d_in[11]; const float* bh = (const float*)d_in[12];
  const float* Wace = (const float*)d_in[13]; const float* bace = (const float*)d_in[14];
  const float* Wh2  = (const float*)d_in[15]; const float* bh2  = (const float*)d_in[16];
  const int* src = ei;
  const int* dst = ei + E;

  // workspace layout (16B-aligned blocks); ~39 MB total
  char* w = (char*)d_ws;
  unsigned long long* degcnt = (unsigned long long*)w;  w += (size_t)N * 8;  // zeroed
  float* dinv   = (float*)w;              w += N * 4;
  unsigned int* slot = (unsigned int*)w;  w += (size_t)N * MAXDEG * 4;   // 12.8 MB
  unsigned short* wt = (unsigned short*)w; w += 3 * 16384 * 2;   // 3 layers f16 [n][k]
  unsigned short* w3kn = (unsigned short*)w; w += 16384 * 2;     // W3 [k][n] f16
  unsigned short* z1 = (unsigned short*)w; w += (size_t)N * D * 2;  // z1 rows (f16)
  unsigned short* z2 = (unsigned short*)w; w += (size_t)N * D * 2;  // z2 rows (f16)

  // ---- build: ONE edge pass (histogram + rank-scatter), then prep ----
  hipMemsetAsync(degcnt, 0, (size_t)N * 8, stream);
  edge_pass_kernel<<<(E + 255) / 256, 256, 0, stream>>>(ew, src, dst, degcnt, slot);
  prep_kernel<<<NB + 192, 256, 0, stream>>>((const uint2*)degcnt, dinv, W1, W2, W3, wt, w3kn);

  const int GB = (N + 127) / 128;  // 391 gemm blocks

  // layer 1: x -> z1 (dinv-scaled)
  gemm_mfma_f32_kernel<<<GB, 256, 0, stream>>>(x, wt + 0 * 16384, dinv, z1);
  // fused agg1 + gemm2: z1 -> h1 (LDS) -> z2 (dinv-scaled)
  agg_gemm_kernel<<<GB, 256, 0, stream>>>(z1, slot, (const uint2*)degcnt, dinv,
                                          b1, wt + 1 * 16384, z2);
  // fused layers 2+3 + dense + heads
  l23_heads_kernel<<<2 * T, 256, 0, stream>>>(z2, slot, (const uint2*)degcnt, dinv,
                                              b2, b3, w3kn, Wh, bh, ace, h2,
                                              Wace, bace, Wh2, bh2, (float*)d_out);
}

// Round 18
// 223.774 us; speedup vs baseline: 1.0977x; 1.0977x over previous
//
#include <hip/hip_runtime.h>
#include <math.h>

constexpr int N = 50000;   // nodes
constexpr int E = 640000;  // edges
constexpr int D = 128;     // dim == hidden
constexpr int T = 100;     // targets per head
constexpr int NB = (N + 255) / 256;  // 196 dinv blocks
constexpr int MAXDEG = 64; // slot capacity; P(Poisson(12.8) >= 64) ~ 1e-24/node
// Per-layer f16 scale: h stored as 256*h. Folded exactly into W1 and biases.
constexpr float SC = 256.0f;
constexpr float SCINV = 1.0f / 256.0f;

typedef __attribute__((ext_vector_type(8))) _Float16 half8v;         // 8 f16 in 4 VGPRs
typedef __attribute__((ext_vector_type(8))) unsigned short ushort8v;
typedef __attribute__((ext_vector_type(4))) float f32x4;             // MFMA accumulator

// ---------------- single-pass edge build: histogram + rank-scatter ----------------
// One 64-bit atomicAdd per edge: high32 accumulates ew in 8.24 fixed (degree),
// low32 counts; the RETURN value's low word is this edge's rank within dst ->
// scatter (ew16|src) into slot[d*MAXDEG+rank]. No second edge pass, no scan.
// (R13 lesson: separate dispatches, never grid.sync on gfx950.)
// (R17 lesson: keep the latency-bound gather kernels SEPARATE from big-LDS GEMMs
//  — fusing halves occupancy and regresses.)

__global__ void edge_pass_kernel(const float* __restrict__ ew, const int* __restrict__ src,
                                 const int* __restrict__ dst,
                                 unsigned long long* __restrict__ degcnt,
                                 unsigned int* __restrict__ slot) {
  int e = blockIdx.x * 256 + threadIdx.x;
  if (e < E) {
    float w = ew[e];
    int d = dst[e];
    unsigned int fxdeg = __float2uint_rn(w * 16777216.0f);       // 8.24 for degree
    unsigned int fx16 = __float2uint_rn(w * 65536.0f);           // 0.16 for agg coef
    if (fx16 > 65535u) fx16 = 65535u;
    unsigned long long old = atomicAdd(&degcnt[d],
                                       ((unsigned long long)fxdeg << 32) | 1ull);
    unsigned int rank = (unsigned int)(old & 0xffffffffull);
    if (rank < MAXDEG)
      slot[(size_t)d * MAXDEG + rank] = (fx16 << 16) | (unsigned int)src[e];
  }
}

// ---------------- prep: dinv (blocks < NB) + W f16 prep (blocks >= NB) ----------------

__global__ __launch_bounds__(256) void prep_kernel(
    const uint2* __restrict__ degcnt, float* __restrict__ dinv,
    const float* __restrict__ W0, const float* __restrict__ W1,
    const float* __restrict__ W2, unsigned short* __restrict__ wt,
    unsigned short* __restrict__ w3kn) {
  if (blockIdx.x < NB) {
    int i = blockIdx.x * 256 + threadIdx.x;
    if (i < N) {
      uint2 p = degcnt[i];                    // .x = count, .y = 8.24 degree sum
      float d = (float)p.y * (1.0f / 16777216.0f) + 1.0f;  // +1 self-loop
      dinv[i] = 1.0f / sqrtf(d);
    }
  } else {
    int idx = (blockIdx.x - NB) * 256 + threadIdx.x;  // 0..49151
    int layer = idx >> 14;
    int r = idx & 16383;
    int k = r & 127, n = r >> 7;
    const float* W = layer == 0 ? W0 : layer == 1 ? W1 : W2;
    float v = W[k * D + n] * (layer == 0 ? SC : 1.0f);
    _Float16 h = (_Float16)v;  // RNE
    unsigned short bits = *(unsigned short*)&h;
    wt[layer * 16384 + n * D + k] = bits;
    if (layer == 2) w3kn[k * D + n] = bits;
  }
}

// ---------------- f16 MFMA GEMM with dinv-scaled epilogue ----------------
// Writes z = dinv[row] * (row @ W)  (x256 scale carried by A or W1).
// B in LDS (34.8 KB -> 4 blocks/CU), 128 rows/block, 4 waves.

__device__ inline void stage_B(const unsigned short* __restrict__ Wt,
                               unsigned short* __restrict__ Bl, int tid) {
  constexpr int SB = 136;
#pragma unroll
  for (int it = 0; it < 8; ++it) {
    int idx = tid + it * 256;          // ushort8 index, 0..2047
    int r = idx >> 4;
    int c8 = idx & 15;
    ushort8v v = *(const ushort8v*)&Wt[r * D + c8 * 8];
    *(ushort8v*)&Bl[r * SB + c8 * 8] = v;
  }
}

__device__ inline void mfma_core_and_store(
    const unsigned short* __restrict__ Bl, half8v (*a)[2], const float* __restrict__ dinv,
    int row0, int rbase, int q, int n16, unsigned short* __restrict__ out) {
  constexpr int SB = 136;
  f32x4 acc[2][8] = {};
#pragma unroll
  for (int kc = 0; kc < 4; ++kc) {
    const int ko = kc * 32 + q * 8;
#pragma unroll
    for (int ct = 0; ct < 8; ++ct) {
      int n = ct * 16 + n16;
      half8v b = *(const half8v*)&Bl[n * SB + ko];
#pragma unroll
      for (int rt = 0; rt < 2; ++rt) {
        acc[rt][ct] = __builtin_amdgcn_mfma_f32_16x16x32_f16(a[kc][rt], b, acc[rt][ct], 0, 0, 0);
      }
    }
  }
#pragma unroll
  for (int rt = 0; rt < 2; ++rt) {
#pragma unroll
    for (int r = 0; r < 4; ++r) {
      int gr = row0 + rbase + rt * 16 + q * 4 + r;
      if (gr < N) {
        float dv = dinv[gr];
#pragma unroll
        for (int ct = 0; ct < 8; ++ct) {
          int col = ct * 16 + n16;
          _Float16 h = (_Float16)(acc[rt][ct][r] * dv);
          out[(size_t)gr * D + col] = *(unsigned short*)&h;
        }
      }
    }
  }
}

__global__ __launch_bounds__(256) void gemm_mfma_kernel(
    const unsigned short* __restrict__ A, const unsigned short* __restrict__ Wt,
    const float* __restrict__ dinv, unsigned short* __restrict__ out) {
  constexpr int SB = 136;
  __shared__ unsigned short Bl[128 * SB];   // 34816 B
  const int tid = threadIdx.x;
  const int row0 = blockIdx.x * 128;
  stage_B(Wt, Bl, tid);
  __syncthreads();

  const int w = tid >> 6, lane = tid & 63;
  const int q = lane >> 4, n16 = lane & 15;
  const int rbase = w * 32;
  size_t arow[2];
#pragma unroll
  for (int rt = 0; rt < 2; ++rt) {
    int gr = row0 + rbase + rt * 16 + n16;
    if (gr >= N) gr = N - 1;
    arow[rt] = (size_t)gr * D;
  }
  half8v a[4][2];
#pragma unroll
  for (int kc = 0; kc < 4; ++kc) {
    const int ko = kc * 32 + q * 8;
#pragma unroll
    for (int rt = 0; rt < 2; ++rt)
      a[kc][rt] = *(const half8v*)&A[arow[rt] + ko];
  }
  mfma_core_and_store(Bl, a, dinv, row0, rbase, q, n16, out);
}

__global__ __launch_bounds__(256) void gemm_mfma_f32_kernel(
    const float* __restrict__ A, const unsigned short* __restrict__ Wt,
    const float* __restrict__ dinv, unsigned short* __restrict__ out) {
  constexpr int SB = 136;
  __shared__ unsigned short Bl[128 * SB];
  const int tid = threadIdx.x;
  const int row0 = blockIdx.x * 128;
  stage_B(Wt, Bl, tid);
  __syncthreads();

  const int w = tid >> 6, lane = tid & 63;
  const int q = lane >> 4, n16 = lane & 15;
  const int rbase = w * 32;
  size_t arow[2];
#pragma unroll
  for (int rt = 0; rt < 2; ++rt) {
    int gr = row0 + rbase + rt * 16 + n16;
    if (gr >= N) gr = N - 1;
    arow[rt] = (size_t)gr * D;
  }
  half8v a[4][2];
#pragma unroll
  for (int kc = 0; kc < 4; ++kc) {
    const int ko = kc * 32 + q * 8;
#pragma unroll
    for (int rt = 0; rt < 2; ++rt) {
      float4 v0 = *(const float4*)&A[arow[rt] + ko];
      float4 v1 = *(const float4*)&A[arow[rt] + ko + 4];
      half8v h;
      h[0] = (_Float16)v0.x; h[1] = (_Float16)v0.y;
      h[2] = (_Float16)v0.z; h[3] = (_Float16)v0.w;
      h[4] = (_Float16)v1.x; h[5] = (_Float16)v1.y;
      h[6] = (_Float16)v1.z; h[7] = (_Float16)v1.w;
      a[kc][rt] = h;
    }
  }
  mfma_core_and_store(Bl, a, dinv, row0, rbase, q, n16, out);
}

// ---------------- pull aggregation over z-rows (layer 1) ----------------
// out(g) = relu(dinv_g * [z(g) + sum ew*z(src)] + 256*b); z rows pre-scaled by dinv.
// 16 lanes/node; slot list is contiguous per node. LDS-free -> high occupancy
// (latency-bound gather needs the waves — R17 lesson).

__global__ __launch_bounds__(256) void agg_kernel(
    const unsigned short* __restrict__ z, const unsigned int* __restrict__ slot,
    const uint2* __restrict__ degcnt, const float* __restrict__ dinv,
    const float* __restrict__ bias, unsigned short* __restrict__ oP) {
  int g = (blockIdx.x * 256 + threadIdx.x) >> 4;
  int lane = threadIdx.x & 15;

  int cnt = (int)degcnt[g].x; if (cnt > MAXDEG) cnt = MAXDEG;
  half8v xv = *(const half8v*)&z[(size_t)g * D + lane * 8];
  float acc[8];
#pragma unroll
  for (int i = 0; i < 8; ++i) acc[i] = (float)xv[i];  // self term: z(g)

  const unsigned int* sl = slot + (size_t)g * MAXDEG;
  int k = 0;
  for (; k + 2 <= cnt; k += 2) {
    unsigned int p0 = sl[k], p1 = sl[k + 1];
    float c0 = (float)(p0 >> 16) * (1.0f / 65536.0f);
    float c1 = (float)(p1 >> 16) * (1.0f / 65536.0f);
    half8v v0 = *(const half8v*)&z[(size_t)(p0 & 0xffffu) * D + lane * 8];
    half8v v1 = *(const half8v*)&z[(size_t)(p1 & 0xffffu) * D + lane * 8];
#pragma unroll
    for (int i = 0; i < 8; ++i) {
      acc[i] = fmaf(c0, (float)v0[i], acc[i]);
      acc[i] = fmaf(c1, (float)v1[i], acc[i]);
    }
  }
  if (k < cnt) {
    unsigned int p = sl[k];
    float c = (float)(p >> 16) * (1.0f / 65536.0f);
    half8v v = *(const half8v*)&z[(size_t)(p & 0xffffu) * D + lane * 8];
#pragma unroll
    for (int i = 0; i < 8; ++i) acc[i] = fmaf(c, (float)v[i], acc[i]);
  }

  float dv = dinv[g];
  half8v hv;
#pragma unroll
  for (int i = 0; i < 8; ++i)
    hv[i] = (_Float16)fmaxf(fmaf(dv, acc[i], bias[lane * 8 + i] * SC), 0.f);
  *(half8v*)&oP[(size_t)g * D + lane * 8] = hv;
}

// ---------------- fused layers 2+3 + dense + heads, per target ----------------
// h2z(u) = dinv_u * relu(dinv_u*[z2(u)+sum ew*z2(s)] + 256*b2)
// svec   = dinv_t * [h2z(t) + sum ew*h2z(src)]
// h3 = relu(svec@W3 + 256*b3)/256; h4 = relu(h3@Wh+bh); out = h4.whead + bhead.

__global__ __launch_bounds__(256) void l23_heads_kernel(
    const unsigned short* __restrict__ z2, const unsigned int* __restrict__ slot,
    const uint2* __restrict__ degcnt, const float* __restrict__ dinv,
    const float* __restrict__ b2, const float* __restrict__ b3,
    const unsigned short* __restrict__ w3kn,
    const float* __restrict__ Wh, const float* __restrict__ bh,
    const int* __restrict__ ace_idx, const int* __restrict__ h2_idx,
    const float* __restrict__ Wace, const float* __restrict__ bace,
    const float* __restrict__ Wh2, const float* __restrict__ bh2,
    float* __restrict__ out) {
  __shared__ float sacc[16][128];        // per-group partial svec (pre dinv_t)
  __shared__ unsigned short w3l[16384];  // W3 [k][n] f16, 32 KB
  __shared__ float svec[128];
  __shared__ float h3v[128];
  __shared__ float psum[2];
  int t = blockIdx.x;       // 0..2T-1
  int tid = threadIdx.x;    // 0..255
  int node; const float* whead; float bhead;
  if (t < T) { node = ace_idx[t];     whead = Wace; bhead = bace[0]; }
  else       { node = h2_idx[t - T];  whead = Wh2;  bhead = bh2[0]; }

#pragma unroll
  for (int it = 0; it < 8; ++it) {
    int idx = tid + it * 256;
    *(ushort8v*)&w3l[idx * 8] = *(const ushort8v*)&w3kn[idx * 8];
  }

  int grp = tid >> 4, lane = tid & 15;
  float b2l[8];
#pragma unroll
  for (int i = 0; i < 8; ++i) b2l[i] = b2[lane * 8 + i] * SC;

  int tcnt = (int)degcnt[node].x; if (tcnt > MAXDEG) tcnt = MAXDEG;
  const unsigned int* tsl = slot + (size_t)node * MAXDEG;
  int nitems = 1 + tcnt;
  float a[8] = {};
  for (int it = grp; it < nitems; it += 16) {
    int u; float wgt;
    if (it == 0) { u = node; wgt = 1.0f; }
    else {
      unsigned int p = tsl[it - 1];
      wgt = (float)(p >> 16) * (1.0f / 65536.0f);
      u = (int)(p & 0xffffu);
    }
    // h2z(u) on the fly
    float dvu = dinv[u];
    half8v xv = *(const half8v*)&z2[(size_t)u * D + lane * 8];
    float r[8];
#pragma unroll
    for (int i = 0; i < 8; ++i) r[i] = (float)xv[i];
    int cu = (int)degcnt[u].x; if (cu > MAXDEG) cu = MAXDEG;
    const unsigned int* usl = slot + (size_t)u * MAXDEG;
    for (int e = 0; e < cu; ++e) {
      unsigned int p2 = usl[e];
      float c2 = (float)(p2 >> 16) * (1.0f / 65536.0f);
      half8v v = *(const half8v*)&z2[(size_t)(p2 & 0xffffu) * D + lane * 8];
#pragma unroll
      for (int i = 0; i < 8; ++i) r[i] = fmaf(c2, (float)v[i], r[i]);
    }
#pragma unroll
    for (int i = 0; i < 8; ++i) {
      float h2 = fmaxf(fmaf(dvu, r[i], b2l[i]), 0.f);
      a[i] = fmaf(wgt, dvu * h2, a[i]);    // accumulate ew * h2z
    }
  }
#pragma unroll
  for (int i = 0; i < 8; ++i) sacc[grp][lane * 8 + i] = a[i];
  __syncthreads();

  // reduce 16 groups -> svec (apply dinv_t here)
  if (tid < 128) {
    float s = 0.f;
#pragma unroll
    for (int gp = 0; gp < 16; ++gp) s += sacc[gp][tid];
    svec[tid] = s * dinv[node];
  }
  __syncthreads();

  if (tid < 128) {
    float y = b3[tid] * SC;
#pragma unroll 16
    for (int k = 0; k < 128; ++k) {
      _Float16 wv = *(const _Float16*)&w3l[k * D + tid];
      y = fmaf(svec[k], (float)wv, y);
    }
    h3v[tid] = fmaxf(y, 0.f) * SCINV;
  }
  __syncthreads();

  float v = 0.f;
  if (tid < 128) {
    float acc = bh[tid];
#pragma unroll 16
    for (int k = 0; k < 128; ++k)
      acc = fmaf(h3v[k], Wh[k * D + tid], acc);
    v = fmaxf(acc, 0.f) * whead[tid];
  }
#pragma unroll
  for (int off = 32; off; off >>= 1) v += __shfl_down(v, off, 64);
  if (tid < 128 && (tid & 63) == 0) psum[tid >> 6] = v;
  __syncthreads();
  if (tid == 0) out[t] = psum[0] + psum[1] + bhead;
}

// ---------------- launch ----------------

extern "C" void kernel_launch(void* const* d_in, const int* in_sizes, int n_in,
                              void* d_out, int out_size, void* d_ws, size_t ws_size,
                              hipStream_t stream) {
  const float* x    = (const float*)d_in[0];
  const int*   ei   = (const int*)d_in[1];
  const float* ew   = (const float*)d_in[2];
  const int*   ace  = (const int*)d_in[3];
  const int*   h2   = (const int*)d_in[4];
  const float* W1 = (const float*)d_in[5];  const float* b1 = (const float*)d_in[6];
  const float* W2 = (const float*)d_in[7];  const float* b2 = (const float*)d_in[8];
  const float* W3 = (const float*)d_in[9];  const float* b3 = (const float*)d_in[10];
  const float* Wh = (const float*)d_in[11]; const float* bh = (const float*)d_in[12];
  const float* Wace = (const float*)d_in[13]; const float* bace = (const float*)d_in[14];
  const float* Wh2  = (const float*)d_in[15]; const float* bh2  = (const float*)d_in[16];
  const int* src = ei;
  const int* dst = ei + E;

  // workspace layout (16B-aligned blocks); ~39 MB total
  char* w = (char*)d_ws;
  unsigned long long* degcnt = (unsigned long long*)w;  w += (size_t)N * 8;  // zeroed
  float* dinv   = (float*)w;              w += N * 4;
  unsigned int* slot = (unsigned int*)w;  w += (size_t)N * MAXDEG * 4;   // 12.8 MB
  unsigned short* wt = (unsigned short*)w; w += 3 * 16384 * 2;   // 3 layers f16 [n][k]
  unsigned short* w3kn = (unsigned short*)w; w += 16384 * 2;     // W3 [k][n] f16
  unsigned short* zbuf = (unsigned short*)w; w += (size_t)N * D * 2;  // z rows (f16)
  unsigned short* P1  = (unsigned short*)w; w += (size_t)N * D * 2;   // h1 rows (f16)

  // ---- build: ONE edge pass (histogram + rank-scatter), then prep ----
  hipMemsetAsync(degcnt, 0, (size_t)N * 8, stream);
  edge_pass_kernel<<<(E + 255) / 256, 256, 0, stream>>>(ew, src, dst, degcnt, slot);
  prep_kernel<<<NB + 192, 256, 0, stream>>>((const uint2*)degcnt, dinv, W1, W2, W3, wt, w3kn);

  const int GB = (N + 127) / 128;  // 391 gemm blocks
  const int AG = N * 16 / 256;     // 3125 agg blocks

  // layer 1: x -> z1 (dinv-scaled) -> P1 = h1
  gemm_mfma_f32_kernel<<<GB, 256, 0, stream>>>(x, wt + 0 * 16384, dinv, zbuf);
  agg_kernel<<<AG, 256, 0, stream>>>(zbuf, slot, (const uint2*)degcnt, dinv, b1, P1);
  // layer 2 gemm: P1 -> z2 (dinv-scaled); layer-2 agg folded into head kernel
  gemm_mfma_kernel<<<GB, 256, 0, stream>>>(P1, wt + 1 * 16384, dinv, zbuf);
  // fused layers 2+3 + dense + heads
  l23_heads_kernel<<<2 * T, 256, 0, stream>>>(zbuf, slot, (const uint2*)degcnt, dinv,
                                              b2, b3, w3kn, Wh, bh, ace, h2,
                                              Wace, bace, Wh2, bh2, (float*)d_out);
}